// Round 25
// baseline (136.664 us; speedup 1.0000x reference)
//
#include <hip/hip_runtime.h>
#include <hip/hip_bf16.h>
#include <math.h>
#include <stdint.h>

// TokenBottleneck v25 — v24 (mask-compacted scorer, best 128.2us) +
// compact writes masked sentinels (tail blocks exit write-free) +
// 32-row gather blocks.
#define BB 8
#define NN 8192
#define HH 1024
#define SS 256
#define KK 1024

// Finite in f32 AND bf16; strictly below any real score (see R3 post-mortem).
#define MASKED_SCORE (-1.0e38f)

typedef _Float16 half8 __attribute__((ext_vector_type(8)));
typedef float f32x4 __attribute__((ext_vector_type(4)));

// ---------------------------------------------------------------------------
// Compact: per batch, stable-partition token indices into
// idxlist[b][0..count)=unmasked, [count..NN)=masked; cnt[b]=count.
// ALSO writes sentinel scores for every masked token (coalesced).
// ---------------------------------------------------------------------------
__global__ __launch_bounds__(1024) void tbv25_compact(
    const int* __restrict__ mask,
    int* __restrict__ idxlist,
    int* __restrict__ cnt,
    float* __restrict__ scores_out)
{
    __shared__ int psum[1024];
    const int b = blockIdx.x, tid = threadIdx.x;
    const int base = tid * 8;
    int mloc[8];
    int c = 0;
#pragma unroll
    for (int i = 0; i < 8; ++i) {
        mloc[i] = mask[(size_t)b * NN + base + i] ? 1 : 0;
        c += mloc[i];
        if (!mloc[i]) scores_out[(size_t)b * NN + base + i] = MASKED_SCORE;
    }
    psum[tid] = c;
    __syncthreads();
    for (int off = 1; off < 1024; off <<= 1) {
        const int add = (tid >= off) ? psum[tid - off] : 0;
        __syncthreads();
        psum[tid] += add;
        __syncthreads();
    }
    const int total = psum[1023];
    const int excl  = psum[tid] - c;
    int upos = excl;
    int mpos = total + (base - excl);
#pragma unroll
    for (int i = 0; i < 8; ++i) {
        const int n = base + i;
        if (mloc[i]) idxlist[(size_t)b * NN + (upos++)] = n;
        else         idxlist[(size_t)b * NN + (mpos++)] = n;
    }
    if (tid == 0) cnt[b] = total;
}

// ---------------------------------------------------------------------------
// Prep: W' = gamma ⊙ w1 split fp16 hi/lo, INTERLEAVED fragment order.
// ---------------------------------------------------------------------------
__global__ __launch_bounds__(256) void tbv25_prep(
    const float* __restrict__ gamma,
    const float* __restrict__ beta,
    const float* __restrict__ w1,
    const float* __restrict__ b1,
    _Float16* __restrict__ wB,
    float* __restrict__ u,
    float* __restrict__ vb)
{
    const int s = blockIdx.x;
    const int tid = threadIdx.x;
    const int fbase = (s >> 4) * 32;
    double ud = 0.0, vd = 0.0;
#pragma unroll
    for (int i = 0; i < 4; ++i) {
        const int k = tid * 4 + i;
        const float wv = gamma[k] * w1[(size_t)k * SS + s];
        const _Float16 hh = (_Float16)wv;
        const _Float16 hl = (_Float16)(wv - (float)hh);
        const int f    = fbase + (k >> 5);
        const int lane = ((k >> 3) & 3) * 16 + (s & 15);
        const size_t idx = (size_t)f * 1024 + lane * 16 + (k & 7);
        wB[idx]     = hh;
        wB[idx + 8] = hl;
        ud += (double)wv;
        vd += (double)beta[k] * (double)w1[(size_t)k * SS + s];
    }
#pragma unroll
    for (int off = 32; off; off >>= 1) {
        ud += __shfl_xor(ud, off, 64);
        vd += __shfl_xor(vd, off, 64);
    }
    __shared__ double su[4], sv[4];
    if ((tid & 63) == 0) { su[tid >> 6] = ud; sv[tid >> 6] = vd; }
    __syncthreads();
    if (tid == 0) {
        u[s]  = (float)(su[0] + su[1] + su[2] + su[3]);
        vb[s] = (float)(sv[0] + sv[1] + sv[2] + sv[3] + (double)b1[s]);
    }
}

// ---------------------------------------------------------------------------
// v25 scorer: v24's (rows gathered via idxlist; tail blocks exit free).
// ---------------------------------------------------------------------------
__global__ __launch_bounds__(512, 4) void tbv25_scorer(
    const float* __restrict__ tokens,
    const _Float16* __restrict__ wB,
    const float* __restrict__ u,
    const float* __restrict__ vb,
    const float* __restrict__ w2,
    const float* __restrict__ b2,
    const int* __restrict__ mask,
    const int* __restrict__ idxlist,
    const int* __restrict__ cnt,
    float* __restrict__ scores_out)
{
    __shared__ _Float16 Ah[2][64 * 64];
    __shared__ _Float16 Al[2][64 * 64];
    __shared__ float rs_s[64], m2_s[64];
    __shared__ float pl[8][64];

    const int tid  = threadIdx.x;
    const int lane = tid & 63;
    const int wid  = tid >> 6;
    const int b    = blockIdx.x >> 7;
    const int lb   = blockIdx.x & 127;
    const int c0   = (blockIdx.x + 5 * (blockIdx.x >> 8)) & 15;

    if (lb * 64 >= cnt[b]) return;         // sentinels already written

    const int* myidx = idxlist + (size_t)b * NN + lb * 64;

    const int srow  = tid >> 3;
    const int scolf = (tid & 7) * 8;
    const int myrow = myidx[srow];
    const float* srcbase = tokens + ((size_t)b * NN + myrow) * HH + scolf;

    float s_acc = 0.f, ss_acc = 0.f;

    f32x4 acc[4][2];
#pragma unroll
    for (int rt = 0; rt < 4; ++rt)
#pragma unroll
        for (int ct = 0; ct < 2; ++ct) acc[rt][ct] = (f32x4){0.f, 0.f, 0.f, 0.f};

    const int arow = lane & 15;
    const int kgrp = (lane >> 4) * 8;
    const int swz  = (srow & 7) << 3;

    auto convert_store8 = [&](float4 v0, float4 v1, int buf) {
        half8 hh, hl;
#pragma unroll
        for (int e = 0; e < 4; ++e) {
            const float x = (e == 0) ? v0.x : (e == 1) ? v0.y : (e == 2) ? v0.z : v0.w;
            s_acc += x; ss_acc += x * x;
            const _Float16 h = (_Float16)x;
            hh[e] = h; hl[e] = (_Float16)(x - (float)h);
        }
#pragma unroll
        for (int e = 0; e < 4; ++e) {
            const float x = (e == 0) ? v1.x : (e == 1) ? v1.y : (e == 2) ? v1.z : v1.w;
            s_acc += x; ss_acc += x * x;
            const _Float16 h = (_Float16)x;
            hh[4 + e] = h; hl[4 + e] = (_Float16)(x - (float)h);
        }
        const int idx = srow * 64 + (scolf ^ swz);
        *reinterpret_cast<half8*>(&Ah[buf][idx]) = hh;
        *reinterpret_cast<half8*>(&Al[buf][idx]) = hl;
    };

    auto loadB = [&](int cc, int k0, half8* bh, half8* bl) {
#pragma unroll
        for (int ct = 0; ct < 2; ++ct) {
            const size_t base = ((size_t)((wid * 2 + ct) * 32 + cc * 2 + k0) * 1024)
                              + lane * 16;
            bh[ct] = *reinterpret_cast<const half8*>(&wB[base]);
            bl[ct] = *reinterpret_cast<const half8*>(&wB[base + 8]);
        }
    };

    auto do_kstep = [&](int buf, int k0, const half8* bh, const half8* bl) {
#pragma unroll
        for (int rt = 0; rt < 4; ++rt) {
            const int row = rt * 16 + arow;
            const int idx = row * 64 + ((k0 * 32 + kgrp) ^ ((row & 7) << 3));
            const half8 ah = *reinterpret_cast<const half8*>(&Ah[buf][idx]);
            const half8 al = *reinterpret_cast<const half8*>(&Al[buf][idx]);
#pragma unroll
            for (int ct = 0; ct < 2; ++ct)
                acc[rt][ct] = __builtin_amdgcn_mfma_f32_16x16x32_f16(
                    ah, bh[ct], acc[rt][ct], 0, 0, 0);
#pragma unroll
            for (int ct = 0; ct < 2; ++ct)
                acc[rt][ct] = __builtin_amdgcn_mfma_f32_16x16x32_f16(
                    al, bh[ct], acc[rt][ct], 0, 0, 0);
#pragma unroll
            for (int ct = 0; ct < 2; ++ct)
                acc[rt][ct] = __builtin_amdgcn_mfma_f32_16x16x32_f16(
                    ah, bl[ct], acc[rt][ct], 0, 0, 0);
        }
    };

    half8 bhA[2], blA[2], bhB[2], blB[2];

    {
        const float* s0 = srcbase + c0 * 64;
        const float4 v0 = *reinterpret_cast<const float4*>(s0);
        const float4 v1 = *reinterpret_cast<const float4*>(s0 + 4);
        convert_store8(v0, v1, 0);
        loadB(c0, 0, bhA, blA);
    }
    __syncthreads();

    for (int c = 0; c < 16; ++c) {
        const int cur = c & 1;
        const int ccn = (c + 1 + c0) & 15;
        float4 v0, v1;
        if (c < 15) {
            const float* s2 = srcbase + (size_t)ccn * 64;
            v0 = *reinterpret_cast<const float4*>(s2);
            v1 = *reinterpret_cast<const float4*>(s2 + 4);
        }
        loadB((c + c0) & 15, 1, bhB, blB);
        do_kstep(cur, 0, bhA, blA);
        if (c < 15) {
            convert_store8(v0, v1, cur ^ 1);
            loadB(ccn, 0, bhA, blA);
        }
        do_kstep(cur, 1, bhB, blB);
        __syncthreads();
    }

#pragma unroll
    for (int off = 4; off; off >>= 1) {
        s_acc  += __shfl_xor(s_acc, off, 64);
        ss_acc += __shfl_xor(ss_acc, off, 64);
    }
    if ((tid & 7) == 0) {
        const double mu  = (double)s_acc * (1.0 / HH);
        const double var = (double)ss_acc * (1.0 / HH) - mu * mu;
        const double rs  = 1.0 / sqrt(var + 1e-5);
        rs_s[srow] = (float)rs;
        m2_s[srow] = (float)(-mu * rs);
    }
    __syncthreads();

    float p[4][4];
#pragma unroll
    for (int rt = 0; rt < 4; ++rt)
#pragma unroll
        for (int q = 0; q < 4; ++q) p[rt][q] = 0.f;
#pragma unroll
    for (int ct = 0; ct < 2; ++ct) {
        const int col = wid * 32 + ct * 16 + arow;
        const float uc  = u[col];
        const float vbc = vb[col];
        const float w2c = w2[col];
#pragma unroll
        for (int rt = 0; rt < 4; ++rt)
#pragma unroll
            for (int q = 0; q < 4; ++q) {
                const int row = rt * 16 + (lane >> 4) * 4 + q;
                const float h = rs_s[row] * acc[rt][ct][q] + m2_s[row] * uc + vbc;
                p[rt][q] += (h > 0.f ? h : 0.f) * w2c;
            }
    }
#pragma unroll
    for (int off = 8; off; off >>= 1)
#pragma unroll
        for (int rt = 0; rt < 4; ++rt)
#pragma unroll
            for (int q = 0; q < 4; ++q)
                p[rt][q] += __shfl_xor(p[rt][q], off, 64);
    if ((lane & 15) == 0)
#pragma unroll
        for (int rt = 0; rt < 4; ++rt)
#pragma unroll
            for (int q = 0; q < 4; ++q)
                pl[wid][rt * 16 + (lane >> 4) * 4 + q] = p[rt][q];
    __syncthreads();

    if (tid < 64) {
        const int n = myidx[tid];
        const size_t tok = (size_t)b * NN + n;
        float scf = pl[0][tid] + pl[1][tid] + pl[2][tid] + pl[3][tid]
                  + pl[4][tid] + pl[5][tid] + pl[6][tid] + pl[7][tid] + b2[0];
        if (mask[tok] == 0) scf = MASKED_SCORE;   // boundary block tail rows
        scores_out[tok] = scf;
    }
}

// ---------------------------------------------------------------------------
// Top-k stage A: slices alternate DESC/ASC; emit top-1024 from correct end.
// ---------------------------------------------------------------------------
__global__ __launch_bounds__(1024) void tbv25_sortslice(
    const float* __restrict__ scores,
    unsigned long long* __restrict__ cand)
{
    __shared__ unsigned long long k[2048];
    const int b = blockIdx.x >> 2, sl = blockIdx.x & 3;
    const bool asc = (sl & 1) != 0;
    const int tid = threadIdx.x;
    const int nbase = sl * 2048;
#pragma unroll
    for (int t = 0; t < 2; ++t) {
        const int i = tid + t * 1024;
        const int n = nbase + i;
        const unsigned int uu = __float_as_uint(scores[(size_t)b * NN + n]);
        const unsigned int ord = (uu & 0x80000000u) ? ~uu : (uu | 0x80000000u);
        k[i] = ((unsigned long long)ord << 32) |
               (unsigned long long)(unsigned int)(NN - 1 - n);
    }
    __syncthreads();
    for (int kk = 2; kk <= 2048; kk <<= 1) {
        for (int j = kk >> 1; j > 0; j >>= 1) {
            const int p = tid;
            const int i1 = 2 * p - (p & (j - 1));
            const int i2 = i1 + j;
            const unsigned long long a = k[i1], c = k[i2];
            const bool up = (i1 & kk) != 0;
            const bool sw = asc ? (up ? (a < c) : (a > c))
                                : (up ? (a > c) : (a < c));
            if (sw) { k[i1] = c; k[i2] = a; }
            __syncthreads();
        }
    }
    cand[(size_t)b * 4096 + sl * 1024 + tid] = asc ? k[1024 + tid] : k[tid];
}

// ---------------------------------------------------------------------------
// Top-k stage B: two 2048 merges (desc/asc) then 4096 desc merge; top-1024.
// ---------------------------------------------------------------------------
__global__ __launch_bounds__(1024) void tbv25_topk4k(
    const unsigned long long* __restrict__ cand,
    const int* __restrict__ mask,
    float* __restrict__ idx_out,
    float* __restrict__ selmask_out)
{
    __shared__ unsigned long long k[4096];
    const int b = blockIdx.x, tid = threadIdx.x;
#pragma unroll
    for (int t = 0; t < 4; ++t)
        k[tid + t * 1024] = cand[(size_t)b * 4096 + tid + t * 1024];
    __syncthreads();

    for (int j = 1024; j > 0; j >>= 1) {
#pragma unroll
        for (int t = 0; t < 2; ++t) {
            const int p   = tid + t * 1024;
            const int seg = p >> 10;
            const int pp  = p & 1023;
            const int i1  = seg * 2048 + 2 * pp - (pp & (j - 1));
            const int i2  = i1 + j;
            const unsigned long long a = k[i1], c = k[i2];
            const bool sw = seg ? (a > c) : (a < c);
            if (sw) { k[i1] = c; k[i2] = a; }
        }
        __syncthreads();
    }

    for (int j = 2048; j > 0; j >>= 1) {
#pragma unroll
        for (int t = 0; t < 2; ++t) {
            const int p  = tid + t * 1024;
            const int i1 = 2 * p - (p & (j - 1));
            const int i2 = i1 + j;
            const unsigned long long a = k[i1], c = k[i2];
            if (a < c) { k[i1] = c; k[i2] = a; }
        }
        __syncthreads();
    }

    const int n = (NN - 1) - (int)(k[tid] & 0xFFFFFFFFull);
    const int m = mask[(size_t)b * NN + n] ? 1 : 0;
    idx_out[(size_t)b * KK + tid]     = (float)n;
    selmask_out[(size_t)b * KK + tid] = (float)m;
}

// ---------------------------------------------------------------------------
// Monolithic top-k fallback (ws-small path).
// ---------------------------------------------------------------------------
__global__ __launch_bounds__(1024) void tbv25_topk_mono(
    const float* __restrict__ scores,
    const int* __restrict__ mask,
    float* __restrict__ idx_out,
    float* __restrict__ selmask_out)
{
    __shared__ unsigned long long k[NN];
    const int b = blockIdx.x, tid = threadIdx.x;
    for (int i = tid; i < NN; i += 1024) {
        const unsigned int uu = __float_as_uint(scores[(size_t)b * NN + i]);
        const unsigned int ord = (uu & 0x80000000u) ? ~uu : (uu | 0x80000000u);
        k[i] = ((unsigned long long)ord << 32) |
               (unsigned long long)(unsigned int)(NN - 1 - i);
    }
    __syncthreads();
    for (int kk = 2; kk <= NN; kk <<= 1) {
        for (int j = kk >> 1; j > 0; j >>= 1) {
            for (int p = tid; p < NN / 2; p += 1024) {
                const int i1 = 2 * p - (p & (j - 1));
                const int i2 = i1 + j;
                const unsigned long long a = k[i1], c = k[i2];
                const bool up = (i1 & kk) != 0;
                const bool sw = up ? (a > c) : (a < c);
                if (sw) { k[i1] = c; k[i2] = a; }
            }
            __syncthreads();
        }
    }
    for (int j = tid; j < KK; j += 1024) {
        const int n = (NN - 1) - (int)(k[j] & 0xFFFFFFFFull);
        const int m = mask[(size_t)b * NN + n] ? 1 : 0;
        idx_out[(size_t)b * KK + j]     = (float)n;
        selmask_out[(size_t)b * KK + j] = (float)m;
    }
}

// ---------------------------------------------------------------------------
// Fallback fp64 scorer (only if ws too small for tables).
// ---------------------------------------------------------------------------
__global__ __launch_bounds__(256) void tbv25_scorer_fp64(
    const float* __restrict__ tokens,
    const float* __restrict__ gamma,
    const float* __restrict__ beta,
    const float* __restrict__ w1,
    const float* __restrict__ b1,
    const float* __restrict__ w2,
    const float* __restrict__ b2,
    const int* __restrict__ mask,
    float* __restrict__ scores_out)
{
    __shared__ float xs[16][HH];
    const int tid = threadIdx.x;
    const size_t tok0 = (size_t)blockIdx.x * 16;
    {
        const float4* src = reinterpret_cast<const float4*>(tokens + tok0 * HH);
        float4* dst = reinterpret_cast<float4*>(&xs[0][0]);
#pragma unroll
        for (int i = 0; i < (16 * HH / 4) / 256; ++i)
            dst[tid + i * 256] = src[tid + i * 256];
    }
    __syncthreads();
    {
        const int row = tid >> 4, l16 = tid & 15;
        double s = 0.0, ss = 0.0;
        for (int h = l16; h < HH; h += 16) {
            const double v = (double)xs[row][h];
            s += v; ss += v * v;
        }
#pragma unroll
        for (int off = 8; off; off >>= 1) {
            s += __shfl_xor(s, off, 64); ss += __shfl_xor(ss, off, 64);
        }
        const double mu = s / HH, var = ss / HH - mu * mu;
        const double rs = 1.0 / sqrt(var + 1e-5);
        for (int h = l16; h < HH; h += 16)
            xs[row][h] = (float)(((double)xs[row][h] - mu) * rs * (double)gamma[h]
                                 + (double)beta[h]);
    }
    __syncthreads();
    const int lane = tid & 63, wv_ = tid >> 6;
    double acc[4][4];
#pragma unroll
    for (int i = 0; i < 4; ++i)
#pragma unroll
        for (int c = 0; c < 4; ++c) acc[i][c] = 0.0;
    for (int h = 0; h < HH; ++h) {
        const float w0 = w1[(size_t)h * SS + lane];
        const float wc1 = w1[(size_t)h * SS + 64 + lane];
        const float wc2 = w1[(size_t)h * SS + 128 + lane];
        const float wc3 = w1[(size_t)h * SS + 192 + lane];
#pragma unroll
        for (int ii = 0; ii < 4; ++ii) {
            const double x0 = (double)xs[wv_ * 4 + ii][h];
            acc[ii][0] += x0 * (double)w0;  acc[ii][1] += x0 * (double)wc1;
            acc[ii][2] += x0 * (double)wc2; acc[ii][3] += x0 * (double)wc3;
        }
    }
    const double b2v = (double)b2[0];
#pragma unroll
    for (int ii = 0; ii < 4; ++ii) {
        double p = 0.0;
#pragma unroll
        for (int c = 0; c < 4; ++c) {
            const int scol = c * 64 + lane;
            double hv = acc[ii][c] + (double)b1[scol];
            hv = hv > 0.0 ? hv : 0.0;
            p += hv * (double)w2[scol];
        }
#pragma unroll
        for (int off = 32; off; off >>= 1) p += __shfl_xor(p, off, 64);
        if (lane == 0) {
            const size_t tok = tok0 + (size_t)wv_ * 4 + ii;
            float scf = (float)(p + b2v);
            if (mask[tok] == 0) scf = MASKED_SCORE;
            scores_out[tok] = scf;
        }
    }
}

// ---------------------------------------------------------------------------
// Gather: 256 blocks x 32 rows each.
// ---------------------------------------------------------------------------
__global__ __launch_bounds__(256) void tbv25_gather(
    const float* __restrict__ tokens,
    const float* __restrict__ idx_out,
    const int* __restrict__ mask,
    float* __restrict__ gathered)
{
    const int base = blockIdx.x * 32;
    const int tid  = threadIdx.x;
#pragma unroll
    for (int it = 0; it < 32; ++it) {
        const int bj = base + it;
        const int b  = bj >> 10;
        const int n  = (int)idx_out[bj];
        const int m  = mask[(size_t)b * NN + n];
        const float4* src =
            reinterpret_cast<const float4*>(tokens + ((size_t)b * NN + n) * HH);
        float4* dst = reinterpret_cast<float4*>(gathered + (size_t)bj * HH);
        float4 v = src[tid];
        if (!m) v = make_float4(0.f, 0.f, 0.f, 0.f);
        dst[tid] = v;
    }
}

// ---------------------------------------------------------------------------
extern "C" void kernel_launch(void* const* d_in, const int* in_sizes, int n_in,
                              void* d_out, int out_size, void* d_ws, size_t ws_size,
                              hipStream_t stream)
{
    const float* tokens = (const float*)d_in[0];
    const float* gamma  = (const float*)d_in[1];
    const float* beta   = (const float*)d_in[2];
    const float* w1     = (const float*)d_in[3];
    const float* b1     = (const float*)d_in[4];
    const float* w2     = (const float*)d_in[5];
    const float* b2     = (const float*)d_in[6];
    const int*   mask   = (const int*)d_in[7];

    float* out      = (float*)d_out;
    float* gathered = out;                                   // B*K*H
    float* idx_out  = out + (size_t)BB * KK * HH;            // B*K
    float* scores   = idx_out + (size_t)BB * KK;             // B*N
    float* selmask  = scores + (size_t)BB * NN;              // B*K

    const size_t wB_bytes   = (size_t)SS * HH * 2 * sizeof(_Float16);   // 1MB
    const size_t uvb_bytes  = 2 * SS * sizeof(float);
    const size_t cand_bytes = (size_t)BB * 4096 * sizeof(unsigned long long);
    const size_t idx_bytes  = (size_t)BB * NN * sizeof(int);            // 256KB
    const size_t cnt_bytes  = BB * sizeof(int);
    const size_t need = wB_bytes + uvb_bytes + cand_bytes + idx_bytes + cnt_bytes;

    if (ws_size >= need) {
        _Float16* wB = (_Float16*)d_ws;
        float* u   = (float*)((char*)d_ws + wB_bytes);
        float* vbp = u + SS;
        unsigned long long* cand =
            (unsigned long long*)((char*)d_ws + wB_bytes + uvb_bytes);
        int* idxlist = (int*)((char*)d_ws + wB_bytes + uvb_bytes + cand_bytes);
        int* cntp    = (int*)((char*)d_ws + wB_bytes + uvb_bytes + cand_bytes + idx_bytes);

        hipLaunchKernelGGL(tbv25_compact, dim3(BB), dim3(1024), 0, stream,
                           mask, idxlist, cntp, scores);
        hipLaunchKernelGGL(tbv25_prep, dim3(SS), dim3(256), 0, stream,
                           gamma, beta, w1, b1, wB, u, vbp);
        hipLaunchKernelGGL(tbv25_scorer, dim3(BB * NN / 64), dim3(512), 0, stream,
                           tokens, wB, u, vbp, w2, b2, mask, idxlist, cntp, scores);
        hipLaunchKernelGGL(tbv25_sortslice, dim3(BB * 4), dim3(1024), 0, stream,
                           scores, cand);
        hipLaunchKernelGGL(tbv25_topk4k, dim3(BB), dim3(1024), 0, stream,
                           cand, mask, idx_out, selmask);
    } else {
        hipLaunchKernelGGL(tbv25_scorer_fp64, dim3(BB * NN / 16), dim3(256), 0, stream,
                           tokens, gamma, beta, w1, b1, w2, b2, mask, scores);
        hipLaunchKernelGGL(tbv25_topk_mono, dim3(BB), dim3(1024), 0, stream,
                           scores, mask, idx_out, selmask);
    }
    hipLaunchKernelGGL(tbv25_gather, dim3(BB * KK / 32), dim3(256), 0, stream,
                       tokens, idx_out, mask, gathered);
}

// Round 26
// 133.268 us; speedup vs baseline: 1.0255x; 1.0255x over previous
//
#include <hip/hip_runtime.h>
#include <hip/hip_bf16.h>
#include <math.h>
#include <stdint.h>

// TokenBottleneck v26 — v24 + compact-sentinel/early-exit (from v25), with
// the 16-row (512-block) gather RESTORED (v25's 32-row gather caused the
// regression: 256 blocks halved scattered-read concurrency).
#define BB 8
#define NN 8192
#define HH 1024
#define SS 256
#define KK 1024

// Finite in f32 AND bf16; strictly below any real score (see R3 post-mortem).
#define MASKED_SCORE (-1.0e38f)

typedef _Float16 half8 __attribute__((ext_vector_type(8)));
typedef float f32x4 __attribute__((ext_vector_type(4)));

// ---------------------------------------------------------------------------
// Compact: per batch, stable-partition token indices into
// idxlist[b][0..count)=unmasked, [count..NN)=masked; cnt[b]=count.
// Also writes sentinel scores for every masked token (coalesced).
// ---------------------------------------------------------------------------
__global__ __launch_bounds__(1024) void tbv26_compact(
    const int* __restrict__ mask,
    int* __restrict__ idxlist,
    int* __restrict__ cnt,
    float* __restrict__ scores_out)
{
    __shared__ int psum[1024];
    const int b = blockIdx.x, tid = threadIdx.x;
    const int base = tid * 8;
    int mloc[8];
    int c = 0;
#pragma unroll
    for (int i = 0; i < 8; ++i) {
        mloc[i] = mask[(size_t)b * NN + base + i] ? 1 : 0;
        c += mloc[i];
        if (!mloc[i]) scores_out[(size_t)b * NN + base + i] = MASKED_SCORE;
    }
    psum[tid] = c;
    __syncthreads();
    for (int off = 1; off < 1024; off <<= 1) {
        const int add = (tid >= off) ? psum[tid - off] : 0;
        __syncthreads();
        psum[tid] += add;
        __syncthreads();
    }
    const int total = psum[1023];
    const int excl  = psum[tid] - c;
    int upos = excl;
    int mpos = total + (base - excl);
#pragma unroll
    for (int i = 0; i < 8; ++i) {
        const int n = base + i;
        if (mloc[i]) idxlist[(size_t)b * NN + (upos++)] = n;
        else         idxlist[(size_t)b * NN + (mpos++)] = n;
    }
    if (tid == 0) cnt[b] = total;
}

// ---------------------------------------------------------------------------
// Prep: W' = gamma ⊙ w1 split fp16 hi/lo, INTERLEAVED fragment order.
// ---------------------------------------------------------------------------
__global__ __launch_bounds__(256) void tbv26_prep(
    const float* __restrict__ gamma,
    const float* __restrict__ beta,
    const float* __restrict__ w1,
    const float* __restrict__ b1,
    _Float16* __restrict__ wB,
    float* __restrict__ u,
    float* __restrict__ vb)
{
    const int s = blockIdx.x;
    const int tid = threadIdx.x;
    const int fbase = (s >> 4) * 32;
    double ud = 0.0, vd = 0.0;
#pragma unroll
    for (int i = 0; i < 4; ++i) {
        const int k = tid * 4 + i;
        const float wv = gamma[k] * w1[(size_t)k * SS + s];
        const _Float16 hh = (_Float16)wv;
        const _Float16 hl = (_Float16)(wv - (float)hh);
        const int f    = fbase + (k >> 5);
        const int lane = ((k >> 3) & 3) * 16 + (s & 15);
        const size_t idx = (size_t)f * 1024 + lane * 16 + (k & 7);
        wB[idx]     = hh;
        wB[idx + 8] = hl;
        ud += (double)wv;
        vd += (double)beta[k] * (double)w1[(size_t)k * SS + s];
    }
#pragma unroll
    for (int off = 32; off; off >>= 1) {
        ud += __shfl_xor(ud, off, 64);
        vd += __shfl_xor(vd, off, 64);
    }
    __shared__ double su[4], sv[4];
    if ((tid & 63) == 0) { su[tid >> 6] = ud; sv[tid >> 6] = vd; }
    __syncthreads();
    if (tid == 0) {
        u[s]  = (float)(su[0] + su[1] + su[2] + su[3]);
        vb[s] = (float)(sv[0] + sv[1] + sv[2] + sv[3] + (double)b1[s]);
    }
}

// ---------------------------------------------------------------------------
// v26 scorer: rows gathered via idxlist; tail blocks exit write-free
// (sentinels pre-written by compact). Per-acc MFMA chain = v5-v25.
// ---------------------------------------------------------------------------
__global__ __launch_bounds__(512, 4) void tbv26_scorer(
    const float* __restrict__ tokens,
    const _Float16* __restrict__ wB,
    const float* __restrict__ u,
    const float* __restrict__ vb,
    const float* __restrict__ w2,
    const float* __restrict__ b2,
    const int* __restrict__ mask,
    const int* __restrict__ idxlist,
    const int* __restrict__ cnt,
    float* __restrict__ scores_out)
{
    __shared__ _Float16 Ah[2][64 * 64];
    __shared__ _Float16 Al[2][64 * 64];
    __shared__ float rs_s[64], m2_s[64];
    __shared__ float pl[8][64];

    const int tid  = threadIdx.x;
    const int lane = tid & 63;
    const int wid  = tid >> 6;
    const int b    = blockIdx.x >> 7;
    const int lb   = blockIdx.x & 127;
    const int c0   = (blockIdx.x + 5 * (blockIdx.x >> 8)) & 15;

    if (lb * 64 >= cnt[b]) return;         // sentinels already written

    const int* myidx = idxlist + (size_t)b * NN + lb * 64;

    const int srow  = tid >> 3;
    const int scolf = (tid & 7) * 8;
    const int myrow = myidx[srow];
    const float* srcbase = tokens + ((size_t)b * NN + myrow) * HH + scolf;

    float s_acc = 0.f, ss_acc = 0.f;

    f32x4 acc[4][2];
#pragma unroll
    for (int rt = 0; rt < 4; ++rt)
#pragma unroll
        for (int ct = 0; ct < 2; ++ct) acc[rt][ct] = (f32x4){0.f, 0.f, 0.f, 0.f};

    const int arow = lane & 15;
    const int kgrp = (lane >> 4) * 8;
    const int swz  = (srow & 7) << 3;

    auto convert_store8 = [&](float4 v0, float4 v1, int buf) {
        half8 hh, hl;
#pragma unroll
        for (int e = 0; e < 4; ++e) {
            const float x = (e == 0) ? v0.x : (e == 1) ? v0.y : (e == 2) ? v0.z : v0.w;
            s_acc += x; ss_acc += x * x;
            const _Float16 h = (_Float16)x;
            hh[e] = h; hl[e] = (_Float16)(x - (float)h);
        }
#pragma unroll
        for (int e = 0; e < 4; ++e) {
            const float x = (e == 0) ? v1.x : (e == 1) ? v1.y : (e == 2) ? v1.z : v1.w;
            s_acc += x; ss_acc += x * x;
            const _Float16 h = (_Float16)x;
            hh[4 + e] = h; hl[4 + e] = (_Float16)(x - (float)h);
        }
        const int idx = srow * 64 + (scolf ^ swz);
        *reinterpret_cast<half8*>(&Ah[buf][idx]) = hh;
        *reinterpret_cast<half8*>(&Al[buf][idx]) = hl;
    };

    auto loadB = [&](int cc, int k0, half8* bh, half8* bl) {
#pragma unroll
        for (int ct = 0; ct < 2; ++ct) {
            const size_t base = ((size_t)((wid * 2 + ct) * 32 + cc * 2 + k0) * 1024)
                              + lane * 16;
            bh[ct] = *reinterpret_cast<const half8*>(&wB[base]);
            bl[ct] = *reinterpret_cast<const half8*>(&wB[base + 8]);
        }
    };

    auto do_kstep = [&](int buf, int k0, const half8* bh, const half8* bl) {
#pragma unroll
        for (int rt = 0; rt < 4; ++rt) {
            const int row = rt * 16 + arow;
            const int idx = row * 64 + ((k0 * 32 + kgrp) ^ ((row & 7) << 3));
            const half8 ah = *reinterpret_cast<const half8*>(&Ah[buf][idx]);
            const half8 al = *reinterpret_cast<const half8*>(&Al[buf][idx]);
#pragma unroll
            for (int ct = 0; ct < 2; ++ct)
                acc[rt][ct] = __builtin_amdgcn_mfma_f32_16x16x32_f16(
                    ah, bh[ct], acc[rt][ct], 0, 0, 0);
#pragma unroll
            for (int ct = 0; ct < 2; ++ct)
                acc[rt][ct] = __builtin_amdgcn_mfma_f32_16x16x32_f16(
                    al, bh[ct], acc[rt][ct], 0, 0, 0);
#pragma unroll
            for (int ct = 0; ct < 2; ++ct)
                acc[rt][ct] = __builtin_amdgcn_mfma_f32_16x16x32_f16(
                    ah, bl[ct], acc[rt][ct], 0, 0, 0);
        }
    };

    half8 bhA[2], blA[2], bhB[2], blB[2];

    {
        const float* s0 = srcbase + c0 * 64;
        const float4 v0 = *reinterpret_cast<const float4*>(s0);
        const float4 v1 = *reinterpret_cast<const float4*>(s0 + 4);
        convert_store8(v0, v1, 0);
        loadB(c0, 0, bhA, blA);
    }
    __syncthreads();

    for (int c = 0; c < 16; ++c) {
        const int cur = c & 1;
        const int ccn = (c + 1 + c0) & 15;
        float4 v0, v1;
        if (c < 15) {
            const float* s2 = srcbase + (size_t)ccn * 64;
            v0 = *reinterpret_cast<const float4*>(s2);
            v1 = *reinterpret_cast<const float4*>(s2 + 4);
        }
        loadB((c + c0) & 15, 1, bhB, blB);
        do_kstep(cur, 0, bhA, blA);
        if (c < 15) {
            convert_store8(v0, v1, cur ^ 1);
            loadB(ccn, 0, bhA, blA);
        }
        do_kstep(cur, 1, bhB, blB);
        __syncthreads();
    }

#pragma unroll
    for (int off = 4; off; off >>= 1) {
        s_acc  += __shfl_xor(s_acc, off, 64);
        ss_acc += __shfl_xor(ss_acc, off, 64);
    }
    if ((tid & 7) == 0) {
        const double mu  = (double)s_acc * (1.0 / HH);
        const double var = (double)ss_acc * (1.0 / HH) - mu * mu;
        const double rs  = 1.0 / sqrt(var + 1e-5);
        rs_s[srow] = (float)rs;
        m2_s[srow] = (float)(-mu * rs);
    }
    __syncthreads();

    float p[4][4];
#pragma unroll
    for (int rt = 0; rt < 4; ++rt)
#pragma unroll
        for (int q = 0; q < 4; ++q) p[rt][q] = 0.f;
#pragma unroll
    for (int ct = 0; ct < 2; ++ct) {
        const int col = wid * 32 + ct * 16 + arow;
        const float uc  = u[col];
        const float vbc = vb[col];
        const float w2c = w2[col];
#pragma unroll
        for (int rt = 0; rt < 4; ++rt)
#pragma unroll
            for (int q = 0; q < 4; ++q) {
                const int row = rt * 16 + (lane >> 4) * 4 + q;
                const float h = rs_s[row] * acc[rt][ct][q] + m2_s[row] * uc + vbc;
                p[rt][q] += (h > 0.f ? h : 0.f) * w2c;
            }
    }
#pragma unroll
    for (int off = 8; off; off >>= 1)
#pragma unroll
        for (int rt = 0; rt < 4; ++rt)
#pragma unroll
            for (int q = 0; q < 4; ++q)
                p[rt][q] += __shfl_xor(p[rt][q], off, 64);
    if ((lane & 15) == 0)
#pragma unroll
        for (int rt = 0; rt < 4; ++rt)
#pragma unroll
            for (int q = 0; q < 4; ++q)
                pl[wid][rt * 16 + (lane >> 4) * 4 + q] = p[rt][q];
    __syncthreads();

    if (tid < 64) {
        const int n = myidx[tid];
        const size_t tok = (size_t)b * NN + n;
        float scf = pl[0][tid] + pl[1][tid] + pl[2][tid] + pl[3][tid]
                  + pl[4][tid] + pl[5][tid] + pl[6][tid] + pl[7][tid] + b2[0];
        if (mask[tok] == 0) scf = MASKED_SCORE;   // boundary block tail rows
        scores_out[tok] = scf;
    }
}

// ---------------------------------------------------------------------------
// Top-k stage A: slices alternate DESC/ASC; emit top-1024 from correct end.
// ---------------------------------------------------------------------------
__global__ __launch_bounds__(1024) void tbv26_sortslice(
    const float* __restrict__ scores,
    unsigned long long* __restrict__ cand)
{
    __shared__ unsigned long long k[2048];
    const int b = blockIdx.x >> 2, sl = blockIdx.x & 3;
    const bool asc = (sl & 1) != 0;
    const int tid = threadIdx.x;
    const int nbase = sl * 2048;
#pragma unroll
    for (int t = 0; t < 2; ++t) {
        const int i = tid + t * 1024;
        const int n = nbase + i;
        const unsigned int uu = __float_as_uint(scores[(size_t)b * NN + n]);
        const unsigned int ord = (uu & 0x80000000u) ? ~uu : (uu | 0x80000000u);
        k[i] = ((unsigned long long)ord << 32) |
               (unsigned long long)(unsigned int)(NN - 1 - n);
    }
    __syncthreads();
    for (int kk = 2; kk <= 2048; kk <<= 1) {
        for (int j = kk >> 1; j > 0; j >>= 1) {
            const int p = tid;
            const int i1 = 2 * p - (p & (j - 1));
            const int i2 = i1 + j;
            const unsigned long long a = k[i1], c = k[i2];
            const bool up = (i1 & kk) != 0;
            const bool sw = asc ? (up ? (a < c) : (a > c))
                                : (up ? (a > c) : (a < c));
            if (sw) { k[i1] = c; k[i2] = a; }
            __syncthreads();
        }
    }
    cand[(size_t)b * 4096 + sl * 1024 + tid] = asc ? k[1024 + tid] : k[tid];
}

// ---------------------------------------------------------------------------
// Top-k stage B: two 2048 merges (desc/asc) then 4096 desc merge; top-1024.
// ---------------------------------------------------------------------------
__global__ __launch_bounds__(1024) void tbv26_topk4k(
    const unsigned long long* __restrict__ cand,
    const int* __restrict__ mask,
    float* __restrict__ idx_out,
    float* __restrict__ selmask_out)
{
    __shared__ unsigned long long k[4096];
    const int b = blockIdx.x, tid = threadIdx.x;
#pragma unroll
    for (int t = 0; t < 4; ++t)
        k[tid + t * 1024] = cand[(size_t)b * 4096 + tid + t * 1024];
    __syncthreads();

    for (int j = 1024; j > 0; j >>= 1) {
#pragma unroll
        for (int t = 0; t < 2; ++t) {
            const int p   = tid + t * 1024;
            const int seg = p >> 10;
            const int pp  = p & 1023;
            const int i1  = seg * 2048 + 2 * pp - (pp & (j - 1));
            const int i2  = i1 + j;
            const unsigned long long a = k[i1], c = k[i2];
            const bool sw = seg ? (a > c) : (a < c);
            if (sw) { k[i1] = c; k[i2] = a; }
        }
        __syncthreads();
    }

    for (int j = 2048; j > 0; j >>= 1) {
#pragma unroll
        for (int t = 0; t < 2; ++t) {
            const int p  = tid + t * 1024;
            const int i1 = 2 * p - (p & (j - 1));
            const int i2 = i1 + j;
            const unsigned long long a = k[i1], c = k[i2];
            if (a < c) { k[i1] = c; k[i2] = a; }
        }
        __syncthreads();
    }

    const int n = (NN - 1) - (int)(k[tid] & 0xFFFFFFFFull);
    const int m = mask[(size_t)b * NN + n] ? 1 : 0;
    idx_out[(size_t)b * KK + tid]     = (float)n;
    selmask_out[(size_t)b * KK + tid] = (float)m;
}

// ---------------------------------------------------------------------------
// Monolithic top-k fallback (ws-small path).
// ---------------------------------------------------------------------------
__global__ __launch_bounds__(1024) void tbv26_topk_mono(
    const float* __restrict__ scores,
    const int* __restrict__ mask,
    float* __restrict__ idx_out,
    float* __restrict__ selmask_out)
{
    __shared__ unsigned long long k[NN];
    const int b = blockIdx.x, tid = threadIdx.x;
    for (int i = tid; i < NN; i += 1024) {
        const unsigned int uu = __float_as_uint(scores[(size_t)b * NN + i]);
        const unsigned int ord = (uu & 0x80000000u) ? ~uu : (uu | 0x80000000u);
        k[i] = ((unsigned long long)ord << 32) |
               (unsigned long long)(unsigned int)(NN - 1 - i);
    }
    __syncthreads();
    for (int kk = 2; kk <= NN; kk <<= 1) {
        for (int j = kk >> 1; j > 0; j >>= 1) {
            for (int p = tid; p < NN / 2; p += 1024) {
                const int i1 = 2 * p - (p & (j - 1));
                const int i2 = i1 + j;
                const unsigned long long a = k[i1], c = k[i2];
                const bool up = (i1 & kk) != 0;
                const bool sw = up ? (a > c) : (a < c);
                if (sw) { k[i1] = c; k[i2] = a; }
            }
            __syncthreads();
        }
    }
    for (int j = tid; j < KK; j += 1024) {
        const int n = (NN - 1) - (int)(k[j] & 0xFFFFFFFFull);
        const int m = mask[(size_t)b * NN + n] ? 1 : 0;
        idx_out[(size_t)b * KK + j]     = (float)n;
        selmask_out[(size_t)b * KK + j] = (float)m;
    }
}

// ---------------------------------------------------------------------------
// Fallback fp64 scorer (only if ws too small for tables).
// ---------------------------------------------------------------------------
__global__ __launch_bounds__(256) void tbv26_scorer_fp64(
    const float* __restrict__ tokens,
    const float* __restrict__ gamma,
    const float* __restrict__ beta,
    const float* __restrict__ w1,
    const float* __restrict__ b1,
    const float* __restrict__ w2,
    const float* __restrict__ b2,
    const int* __restrict__ mask,
    float* __restrict__ scores_out)
{
    __shared__ float xs[16][HH];
    const int tid = threadIdx.x;
    const size_t tok0 = (size_t)blockIdx.x * 16;
    {
        const float4* src = reinterpret_cast<const float4*>(tokens + tok0 * HH);
        float4* dst = reinterpret_cast<float4*>(&xs[0][0]);
#pragma unroll
        for (int i = 0; i < (16 * HH / 4) / 256; ++i)
            dst[tid + i * 256] = src[tid + i * 256];
    }
    __syncthreads();
    {
        const int row = tid >> 4, l16 = tid & 15;
        double s = 0.0, ss = 0.0;
        for (int h = l16; h < HH; h += 16) {
            const double v = (double)xs[row][h];
            s += v; ss += v * v;
        }
#pragma unroll
        for (int off = 8; off; off >>= 1) {
            s += __shfl_xor(s, off, 64); ss += __shfl_xor(ss, off, 64);
        }
        const double mu = s / HH, var = ss / HH - mu * mu;
        const double rs = 1.0 / sqrt(var + 1e-5);
        for (int h = l16; h < HH; h += 16)
            xs[row][h] = (float)(((double)xs[row][h] - mu) * rs * (double)gamma[h]
                                 + (double)beta[h]);
    }
    __syncthreads();
    const int lane = tid & 63, wv_ = tid >> 6;
    double acc[4][4];
#pragma unroll
    for (int i = 0; i < 4; ++i)
#pragma unroll
        for (int c = 0; c < 4; ++c) acc[i][c] = 0.0;
    for (int h = 0; h < HH; ++h) {
        const float w0 = w1[(size_t)h * SS + lane];
        const float wc1 = w1[(size_t)h * SS + 64 + lane];
        const float wc2 = w1[(size_t)h * SS + 128 + lane];
        const float wc3 = w1[(size_t)h * SS + 192 + lane];
#pragma unroll
        for (int ii = 0; ii < 4; ++ii) {
            const double x0 = (double)xs[wv_ * 4 + ii][h];
            acc[ii][0] += x0 * (double)w0;  acc[ii][1] += x0 * (double)wc1;
            acc[ii][2] += x0 * (double)wc2; acc[ii][3] += x0 * (double)wc3;
        }
    }
    const double b2v = (double)b2[0];
#pragma unroll
    for (int ii = 0; ii < 4; ++ii) {
        double p = 0.0;
#pragma unroll
        for (int c = 0; c < 4; ++c) {
            const int scol = c * 64 + lane;
            double hv = acc[ii][c] + (double)b1[scol];
            hv = hv > 0.0 ? hv : 0.0;
            p += hv * (double)w2[scol];
        }
#pragma unroll
        for (int off = 32; off; off >>= 1) p += __shfl_xor(p, off, 64);
        if (lane == 0) {
            const size_t tok = tok0 + (size_t)wv_ * 4 + ii;
            float scf = (float)(p + b2v);
            if (mask[tok] == 0) scf = MASKED_SCORE;
            scores_out[tok] = scf;
        }
    }
}

// ---------------------------------------------------------------------------
// Gather: 512 blocks x 16 rows each (v24's proven config).
// ---------------------------------------------------------------------------
__global__ __launch_bounds__(256) void tbv26_gather(
    const float* __restrict__ tokens,
    const float* __restrict__ idx_out,
    const int* __restrict__ mask,
    float* __restrict__ gathered)
{
    const int base = blockIdx.x * 16;
    const int tid  = threadIdx.x;
#pragma unroll
    for (int it = 0; it < 16; ++it) {
        const int bj = base + it;
        const int b  = bj >> 10;
        const int n  = (int)idx_out[bj];
        const int m  = mask[(size_t)b * NN + n];
        const float4* src =
            reinterpret_cast<const float4*>(tokens + ((size_t)b * NN + n) * HH);
        float4* dst = reinterpret_cast<float4*>(gathered + (size_t)bj * HH);
        float4 v = src[tid];
        if (!m) v = make_float4(0.f, 0.f, 0.f, 0.f);
        dst[tid] = v;
    }
}

// ---------------------------------------------------------------------------
extern "C" void kernel_launch(void* const* d_in, const int* in_sizes, int n_in,
                              void* d_out, int out_size, void* d_ws, size_t ws_size,
                              hipStream_t stream)
{
    const float* tokens = (const float*)d_in[0];
    const float* gamma  = (const float*)d_in[1];
    const float* beta   = (const float*)d_in[2];
    const float* w1     = (const float*)d_in[3];
    const float* b1     = (const float*)d_in[4];
    const float* w2     = (const float*)d_in[5];
    const float* b2     = (const float*)d_in[6];
    const int*   mask   = (const int*)d_in[7];

    float* out      = (float*)d_out;
    float* gathered = out;                                   // B*K*H
    float* idx_out  = out + (size_t)BB * KK * HH;            // B*K
    float* scores   = idx_out + (size_t)BB * KK;             // B*N
    float* selmask  = scores + (size_t)BB * NN;              // B*K

    const size_t wB_bytes   = (size_t)SS * HH * 2 * sizeof(_Float16);   // 1MB
    const size_t uvb_bytes  = 2 * SS * sizeof(float);
    const size_t cand_bytes = (size_t)BB * 4096 * sizeof(unsigned long long);
    const size_t idx_bytes  = (size_t)BB * NN * sizeof(int);            // 256KB
    const size_t cnt_bytes  = BB * sizeof(int);
    const size_t need = wB_bytes + uvb_bytes + cand_bytes + idx_bytes + cnt_bytes;

    if (ws_size >= need) {
        _Float16* wB = (_Float16*)d_ws;
        float* u   = (float*)((char*)d_ws + wB_bytes);
        float* vbp = u + SS;
        unsigned long long* cand =
            (unsigned long long*)((char*)d_ws + wB_bytes + uvb_bytes);
        int* idxlist = (int*)((char*)d_ws + wB_bytes + uvb_bytes + cand_bytes);
        int* cntp    = (int*)((char*)d_ws + wB_bytes + uvb_bytes + cand_bytes + idx_bytes);

        hipLaunchKernelGGL(tbv26_compact, dim3(BB), dim3(1024), 0, stream,
                           mask, idxlist, cntp, scores);
        hipLaunchKernelGGL(tbv26_prep, dim3(SS), dim3(256), 0, stream,
                           gamma, beta, w1, b1, wB, u, vbp);
        hipLaunchKernelGGL(tbv26_scorer, dim3(BB * NN / 64), dim3(512), 0, stream,
                           tokens, wB, u, vbp, w2, b2, mask, idxlist, cntp, scores);
        hipLaunchKernelGGL(tbv26_sortslice, dim3(BB * 4), dim3(1024), 0, stream,
                           scores, cand);
        hipLaunchKernelGGL(tbv26_topk4k, dim3(BB), dim3(1024), 0, stream,
                           cand, mask, idx_out, selmask);
    } else {
        hipLaunchKernelGGL(tbv26_scorer_fp64, dim3(BB * NN / 16), dim3(256), 0, stream,
                           tokens, gamma, beta, w1, b1, w2, b2, mask, scores);
        hipLaunchKernelGGL(tbv26_topk_mono, dim3(BB), dim3(1024), 0, stream,
                           scores, mask, idx_out, selmask);
    }
    hipLaunchKernelGGL(tbv26_gather, dim3(BB * KK / 16), dim3(256), 0, stream,
                       tokens, idx_out, mask, gathered);
}

// Round 27
// 126.078 us; speedup vs baseline: 1.0840x; 1.0570x over previous
//
#include <hip/hip_runtime.h>
#include <hip/hip_bf16.h>
#include <math.h>
#include <stdint.h>

// TokenBottleneck FINAL (= v24, best measured: 128.2us).
// Pipeline: compact(mask) -> prep(W' fp16 hi/lo split) -> MFMA scorer over
// unmasked rows only -> sliced bitonic top-k (sort+merge) -> batched gather.
// Scorer: BM=64, 512thr (8 waves, wave w -> cols [w*32,+32), rt=4 ct=2,
// acc=32 AGPR), BK=64 dbuf LDS, 2 blocks/CU, B reg-prefetch, chunk stagger.
// Numerics: fp16 two-way-split 3-term MFMA GEMM (x=xh+xl, w=wh+wl; terms
// xh·wh + xl·wh + xh·wl in f32 MFMA accum) with LN folded algebraically:
// score = w2 · relu(rs·(x@W') − mu·rs·u + vb) + b2.
#define BB 8
#define NN 8192
#define HH 1024
#define SS 256
#define KK 1024

// Finite in f32 AND bf16; strictly below any real score (R3 post-mortem:
// -inf and -FLT_MAX both become -inf under the harness's bf16 quantization,
// making abs((-inf)-(-inf))=nan fail the scores output).
#define MASKED_SCORE (-1.0e38f)

typedef _Float16 half8 __attribute__((ext_vector_type(8)));
typedef float f32x4 __attribute__((ext_vector_type(4)));

// ---------------------------------------------------------------------------
// Compact: per batch, stable-partition token indices into
// idxlist[b][0..count) = unmasked, [count..NN) = masked. cnt[b] = count.
// 1024 threads, 8 elements each, Hillis-Steele scan in LDS.
// ---------------------------------------------------------------------------
__global__ __launch_bounds__(1024) void tbf_compact(
    const int* __restrict__ mask,
    int* __restrict__ idxlist,
    int* __restrict__ cnt)
{
    __shared__ int psum[1024];
    const int b = blockIdx.x, tid = threadIdx.x;
    const int base = tid * 8;
    int mloc[8];
    int c = 0;
#pragma unroll
    for (int i = 0; i < 8; ++i) {
        mloc[i] = mask[(size_t)b * NN + base + i] ? 1 : 0;
        c += mloc[i];
    }
    psum[tid] = c;
    __syncthreads();
    for (int off = 1; off < 1024; off <<= 1) {
        const int add = (tid >= off) ? psum[tid - off] : 0;
        __syncthreads();
        psum[tid] += add;
        __syncthreads();
    }
    const int total = psum[1023];
    const int excl  = psum[tid] - c;         // unmasked before my range
    int upos = excl;
    int mpos = total + (base - excl);        // masked before my range
#pragma unroll
    for (int i = 0; i < 8; ++i) {
        const int n = base + i;
        if (mloc[i]) idxlist[(size_t)b * NN + (upos++)] = n;
        else         idxlist[(size_t)b * NN + (mpos++)] = n;
    }
    if (tid == 0) cnt[b] = total;
}

// ---------------------------------------------------------------------------
// Prep: W' = gamma ⊙ w1 split fp16 hi/lo, INTERLEAVED fragment order:
// element (s,k): f=(s>>4)*32+(k>>5), lane=((k>>3)&3)*16+(s&15), j=k&7;
// hi at wB[f*1024 + lane*16 + j], lo at +8. u[s]=Σ γ w1; vb[s]=Σ β w1 + b1.
// ---------------------------------------------------------------------------
__global__ __launch_bounds__(256) void tbf_prep(
    const float* __restrict__ gamma,
    const float* __restrict__ beta,
    const float* __restrict__ w1,
    const float* __restrict__ b1,
    _Float16* __restrict__ wB,
    float* __restrict__ u,
    float* __restrict__ vb)
{
    const int s = blockIdx.x;
    const int tid = threadIdx.x;
    const int fbase = (s >> 4) * 32;
    double ud = 0.0, vd = 0.0;
#pragma unroll
    for (int i = 0; i < 4; ++i) {
        const int k = tid * 4 + i;
        const float wv = gamma[k] * w1[(size_t)k * SS + s];
        const _Float16 hh = (_Float16)wv;
        const _Float16 hl = (_Float16)(wv - (float)hh);
        const int f    = fbase + (k >> 5);
        const int lane = ((k >> 3) & 3) * 16 + (s & 15);
        const size_t idx = (size_t)f * 1024 + lane * 16 + (k & 7);
        wB[idx]     = hh;
        wB[idx + 8] = hl;
        ud += (double)wv;
        vd += (double)beta[k] * (double)w1[(size_t)k * SS + s];
    }
#pragma unroll
    for (int off = 32; off; off >>= 1) {
        ud += __shfl_xor(ud, off, 64);
        vd += __shfl_xor(vd, off, 64);
    }
    __shared__ double su[4], sv[4];
    if ((tid & 63) == 0) { su[tid >> 6] = ud; sv[tid >> 6] = vd; }
    __syncthreads();
    if (tid == 0) {
        u[s]  = (float)(su[0] + su[1] + su[2] + su[3]);
        vb[s] = (float)(sv[0] + sv[1] + sv[2] + sv[3] + (double)b1[s]);
    }
}

// ---------------------------------------------------------------------------
// Scorer: the 64 rows are GATHERED via idxlist. Grid 1024 blocks:
// b = blk>>7, lb = blk&127. Blocks with lb*64 >= cnt[b] write sentinels
// and exit. Per-acc MFMA chain: ah·bh -> al·bh -> ah·bl, k ascending.
// ---------------------------------------------------------------------------
__global__ __launch_bounds__(512, 4) void tbf_scorer(
    const float* __restrict__ tokens,
    const _Float16* __restrict__ wB,
    const float* __restrict__ u,
    const float* __restrict__ vb,
    const float* __restrict__ w2,
    const float* __restrict__ b2,
    const int* __restrict__ mask,
    const int* __restrict__ idxlist,
    const int* __restrict__ cnt,
    float* __restrict__ scores_out)
{
    __shared__ _Float16 Ah[2][64 * 64];
    __shared__ _Float16 Al[2][64 * 64];
    __shared__ float rs_s[64], m2_s[64];
    __shared__ float pl[8][64];

    const int tid  = threadIdx.x;
    const int lane = tid & 63;
    const int wid  = tid >> 6;
    const int b    = blockIdx.x >> 7;
    const int lb   = blockIdx.x & 127;
    const int c0   = (blockIdx.x + 5 * (blockIdx.x >> 8)) & 15;

    const int* myidx = idxlist + (size_t)b * NN + lb * 64;

    if (lb * 64 >= cnt[b]) {               // whole block in masked tail
        if (tid < 64)
            scores_out[(size_t)b * NN + myidx[tid]] = MASKED_SCORE;
        return;
    }

    const int srow  = tid >> 3;
    const int scolf = (tid & 7) * 8;
    const int myrow = myidx[srow];         // gathered token row
    const float* srcbase = tokens + ((size_t)b * NN + myrow) * HH + scolf;

    float s_acc = 0.f, ss_acc = 0.f;

    f32x4 acc[4][2];
#pragma unroll
    for (int rt = 0; rt < 4; ++rt)
#pragma unroll
        for (int ct = 0; ct < 2; ++ct) acc[rt][ct] = (f32x4){0.f, 0.f, 0.f, 0.f};

    const int arow = lane & 15;
    const int kgrp = (lane >> 4) * 8;
    const int swz  = (srow & 7) << 3;

    auto convert_store8 = [&](float4 v0, float4 v1, int buf) {
        half8 hh, hl;
#pragma unroll
        for (int e = 0; e < 4; ++e) {
            const float x = (e == 0) ? v0.x : (e == 1) ? v0.y : (e == 2) ? v0.z : v0.w;
            s_acc += x; ss_acc += x * x;
            const _Float16 h = (_Float16)x;
            hh[e] = h; hl[e] = (_Float16)(x - (float)h);
        }
#pragma unroll
        for (int e = 0; e < 4; ++e) {
            const float x = (e == 0) ? v1.x : (e == 1) ? v1.y : (e == 2) ? v1.z : v1.w;
            s_acc += x; ss_acc += x * x;
            const _Float16 h = (_Float16)x;
            hh[4 + e] = h; hl[4 + e] = (_Float16)(x - (float)h);
        }
        const int idx = srow * 64 + (scolf ^ swz);
        *reinterpret_cast<half8*>(&Ah[buf][idx]) = hh;
        *reinterpret_cast<half8*>(&Al[buf][idx]) = hl;
    };

    auto loadB = [&](int cc, int k0, half8* bh, half8* bl) {
#pragma unroll
        for (int ct = 0; ct < 2; ++ct) {
            const size_t base = ((size_t)((wid * 2 + ct) * 32 + cc * 2 + k0) * 1024)
                              + lane * 16;
            bh[ct] = *reinterpret_cast<const half8*>(&wB[base]);
            bl[ct] = *reinterpret_cast<const half8*>(&wB[base + 8]);
        }
    };

    auto do_kstep = [&](int buf, int k0, const half8* bh, const half8* bl) {
#pragma unroll
        for (int rt = 0; rt < 4; ++rt) {
            const int row = rt * 16 + arow;
            const int idx = row * 64 + ((k0 * 32 + kgrp) ^ ((row & 7) << 3));
            const half8 ah = *reinterpret_cast<const half8*>(&Ah[buf][idx]);
            const half8 al = *reinterpret_cast<const half8*>(&Al[buf][idx]);
#pragma unroll
            for (int ct = 0; ct < 2; ++ct)
                acc[rt][ct] = __builtin_amdgcn_mfma_f32_16x16x32_f16(
                    ah, bh[ct], acc[rt][ct], 0, 0, 0);
#pragma unroll
            for (int ct = 0; ct < 2; ++ct)
                acc[rt][ct] = __builtin_amdgcn_mfma_f32_16x16x32_f16(
                    al, bh[ct], acc[rt][ct], 0, 0, 0);
#pragma unroll
            for (int ct = 0; ct < 2; ++ct)
                acc[rt][ct] = __builtin_amdgcn_mfma_f32_16x16x32_f16(
                    ah, bl[ct], acc[rt][ct], 0, 0, 0);
        }
    };

    half8 bhA[2], blA[2], bhB[2], blB[2];

    {
        const float* s0 = srcbase + c0 * 64;
        const float4 v0 = *reinterpret_cast<const float4*>(s0);
        const float4 v1 = *reinterpret_cast<const float4*>(s0 + 4);
        convert_store8(v0, v1, 0);
        loadB(c0, 0, bhA, blA);
    }
    __syncthreads();

    for (int c = 0; c < 16; ++c) {
        const int cur = c & 1;
        const int ccn = (c + 1 + c0) & 15;
        float4 v0, v1;
        if (c < 15) {
            const float* s2 = srcbase + (size_t)ccn * 64;
            v0 = *reinterpret_cast<const float4*>(s2);
            v1 = *reinterpret_cast<const float4*>(s2 + 4);
        }
        loadB((c + c0) & 15, 1, bhB, blB);
        do_kstep(cur, 0, bhA, blA);
        if (c < 15) {
            convert_store8(v0, v1, cur ^ 1);
            loadB(ccn, 0, bhA, blA);
        }
        do_kstep(cur, 1, bhB, blB);
        __syncthreads();
    }

#pragma unroll
    for (int off = 4; off; off >>= 1) {
        s_acc  += __shfl_xor(s_acc, off, 64);
        ss_acc += __shfl_xor(ss_acc, off, 64);
    }
    if ((tid & 7) == 0) {
        const double mu  = (double)s_acc * (1.0 / HH);
        const double var = (double)ss_acc * (1.0 / HH) - mu * mu;
        const double rs  = 1.0 / sqrt(var + 1e-5);
        rs_s[srow] = (float)rs;
        m2_s[srow] = (float)(-mu * rs);
    }
    __syncthreads();

    float p[4][4];
#pragma unroll
    for (int rt = 0; rt < 4; ++rt)
#pragma unroll
        for (int q = 0; q < 4; ++q) p[rt][q] = 0.f;
#pragma unroll
    for (int ct = 0; ct < 2; ++ct) {
        const int col = wid * 32 + ct * 16 + arow;
        const float uc  = u[col];
        const float vbc = vb[col];
        const float w2c = w2[col];
#pragma unroll
        for (int rt = 0; rt < 4; ++rt)
#pragma unroll
            for (int q = 0; q < 4; ++q) {
                const int row = rt * 16 + (lane >> 4) * 4 + q;
                const float h = rs_s[row] * acc[rt][ct][q] + m2_s[row] * uc + vbc;
                p[rt][q] += (h > 0.f ? h : 0.f) * w2c;
            }
    }
#pragma unroll
    for (int off = 8; off; off >>= 1)
#pragma unroll
        for (int rt = 0; rt < 4; ++rt)
#pragma unroll
            for (int q = 0; q < 4; ++q)
                p[rt][q] += __shfl_xor(p[rt][q], off, 64);
    if ((lane & 15) == 0)
#pragma unroll
        for (int rt = 0; rt < 4; ++rt)
#pragma unroll
            for (int q = 0; q < 4; ++q)
                pl[wid][rt * 16 + (lane >> 4) * 4 + q] = p[rt][q];
    __syncthreads();

    if (tid < 64) {
        const int n = myidx[tid];
        const size_t tok = (size_t)b * NN + n;
        float scf = pl[0][tid] + pl[1][tid] + pl[2][tid] + pl[3][tid]
                  + pl[4][tid] + pl[5][tid] + pl[6][tid] + pl[7][tid] + b2[0];
        if (mask[tok] == 0) scf = MASKED_SCORE;   // boundary block's tail rows
        scores_out[tok] = scf;
    }
}

// ---------------------------------------------------------------------------
// Top-k stage A: per (batch, slice-of-2048) bitonic sort; slices alternate
// DESC (sl even) / ASC (sl odd). Emit top-1024 from the correct end so
// cand = [desc1024 | asc1024 | desc1024 | asc1024] (valley pairs -> bitonic).
// ---------------------------------------------------------------------------
__global__ __launch_bounds__(1024) void tbf_sortslice(
    const float* __restrict__ scores,
    unsigned long long* __restrict__ cand)
{
    __shared__ unsigned long long k[2048];
    const int b = blockIdx.x >> 2, sl = blockIdx.x & 3;
    const bool asc = (sl & 1) != 0;
    const int tid = threadIdx.x;
    const int nbase = sl * 2048;
#pragma unroll
    for (int t = 0; t < 2; ++t) {
        const int i = tid + t * 1024;
        const int n = nbase + i;
        const unsigned int uu = __float_as_uint(scores[(size_t)b * NN + n]);
        const unsigned int ord = (uu & 0x80000000u) ? ~uu : (uu | 0x80000000u);
        k[i] = ((unsigned long long)ord << 32) |
               (unsigned long long)(unsigned int)(NN - 1 - n);
    }
    __syncthreads();
    for (int kk = 2; kk <= 2048; kk <<= 1) {
        for (int j = kk >> 1; j > 0; j >>= 1) {
            const int p = tid;
            const int i1 = 2 * p - (p & (j - 1));
            const int i2 = i1 + j;
            const unsigned long long a = k[i1], c = k[i2];
            const bool up = (i1 & kk) != 0;
            const bool sw = asc ? (up ? (a < c) : (a > c))
                                : (up ? (a > c) : (a < c));
            if (sw) { k[i1] = c; k[i2] = a; }
            __syncthreads();
        }
    }
    cand[(size_t)b * 4096 + sl * 1024 + tid] = asc ? k[1024 + tid] : k[tid];
}

// ---------------------------------------------------------------------------
// Top-k stage B: phase 1 = two 2048 bitonic merges (seg0 desc, seg1 asc);
// phase 2 = [desc2048|asc2048] valley -> 4096 desc merge. Emit top-1024
// (exact jax.lax.top_k ordering; composite keys are unique).
// ---------------------------------------------------------------------------
__global__ __launch_bounds__(1024) void tbf_topk4k(
    const unsigned long long* __restrict__ cand,
    const int* __restrict__ mask,
    float* __restrict__ idx_out,
    float* __restrict__ selmask_out)
{
    __shared__ unsigned long long k[4096];
    const int b = blockIdx.x, tid = threadIdx.x;
#pragma unroll
    for (int t = 0; t < 4; ++t)
        k[tid + t * 1024] = cand[(size_t)b * 4096 + tid + t * 1024];
    __syncthreads();

    for (int j = 1024; j > 0; j >>= 1) {
#pragma unroll
        for (int t = 0; t < 2; ++t) {
            const int p   = tid + t * 1024;
            const int seg = p >> 10;
            const int pp  = p & 1023;
            const int i1  = seg * 2048 + 2 * pp - (pp & (j - 1));
            const int i2  = i1 + j;
            const unsigned long long a = k[i1], c = k[i2];
            const bool sw = seg ? (a > c) : (a < c);
            if (sw) { k[i1] = c; k[i2] = a; }
        }
        __syncthreads();
    }

    for (int j = 2048; j > 0; j >>= 1) {
#pragma unroll
        for (int t = 0; t < 2; ++t) {
            const int p  = tid + t * 1024;
            const int i1 = 2 * p - (p & (j - 1));
            const int i2 = i1 + j;
            const unsigned long long a = k[i1], c = k[i2];
            if (a < c) { k[i1] = c; k[i2] = a; }
        }
        __syncthreads();
    }

    const int n = (NN - 1) - (int)(k[tid] & 0xFFFFFFFFull);
    const int m = mask[(size_t)b * NN + n] ? 1 : 0;
    idx_out[(size_t)b * KK + tid]     = (float)n;
    selmask_out[(size_t)b * KK + tid] = (float)m;
}

// ---------------------------------------------------------------------------
// Monolithic top-k fallback (ws-small path).
// ---------------------------------------------------------------------------
__global__ __launch_bounds__(1024) void tbf_topk_mono(
    const float* __restrict__ scores,
    const int* __restrict__ mask,
    float* __restrict__ idx_out,
    float* __restrict__ selmask_out)
{
    __shared__ unsigned long long k[NN];
    const int b = blockIdx.x, tid = threadIdx.x;
    for (int i = tid; i < NN; i += 1024) {
        const unsigned int uu = __float_as_uint(scores[(size_t)b * NN + i]);
        const unsigned int ord = (uu & 0x80000000u) ? ~uu : (uu | 0x80000000u);
        k[i] = ((unsigned long long)ord << 32) |
               (unsigned long long)(unsigned int)(NN - 1 - i);
    }
    __syncthreads();
    for (int kk = 2; kk <= NN; kk <<= 1) {
        for (int j = kk >> 1; j > 0; j >>= 1) {
            for (int p = tid; p < NN / 2; p += 1024) {
                const int i1 = 2 * p - (p & (j - 1));
                const int i2 = i1 + j;
                const unsigned long long a = k[i1], c = k[i2];
                const bool up = (i1 & kk) != 0;
                const bool sw = up ? (a > c) : (a < c);
                if (sw) { k[i1] = c; k[i2] = a; }
            }
            __syncthreads();
        }
    }
    for (int j = tid; j < KK; j += 1024) {
        const int n = (NN - 1) - (int)(k[j] & 0xFFFFFFFFull);
        const int m = mask[(size_t)b * NN + n] ? 1 : 0;
        idx_out[(size_t)b * KK + j]     = (float)n;
        selmask_out[(size_t)b * KK + j] = (float)m;
    }
}

// ---------------------------------------------------------------------------
// Fallback fp64 scorer (only if ws too small for tables).
// ---------------------------------------------------------------------------
__global__ __launch_bounds__(256) void tbf_scorer_fp64(
    const float* __restrict__ tokens,
    const float* __restrict__ gamma,
    const float* __restrict__ beta,
    const float* __restrict__ w1,
    const float* __restrict__ b1,
    const float* __restrict__ w2,
    const float* __restrict__ b2,
    const int* __restrict__ mask,
    float* __restrict__ scores_out)
{
    __shared__ float xs[16][HH];
    const int tid = threadIdx.x;
    const size_t tok0 = (size_t)blockIdx.x * 16;
    {
        const float4* src = reinterpret_cast<const float4*>(tokens + tok0 * HH);
        float4* dst = reinterpret_cast<float4*>(&xs[0][0]);
#pragma unroll
        for (int i = 0; i < (16 * HH / 4) / 256; ++i)
            dst[tid + i * 256] = src[tid + i * 256];
    }
    __syncthreads();
    {
        const int row = tid >> 4, l16 = tid & 15;
        double s = 0.0, ss = 0.0;
        for (int h = l16; h < HH; h += 16) {
            const double v = (double)xs[row][h];
            s += v; ss += v * v;
        }
#pragma unroll
        for (int off = 8; off; off >>= 1) {
            s += __shfl_xor(s, off, 64); ss += __shfl_xor(ss, off, 64);
        }
        const double mu = s / HH, var = ss / HH - mu * mu;
        const double rs = 1.0 / sqrt(var + 1e-5);
        for (int h = l16; h < HH; h += 16)
            xs[row][h] = (float)(((double)xs[row][h] - mu) * rs * (double)gamma[h]
                                 + (double)beta[h]);
    }
    __syncthreads();
    const int lane = tid & 63, wv_ = tid >> 6;
    double acc[4][4];
#pragma unroll
    for (int i = 0; i < 4; ++i)
#pragma unroll
        for (int c = 0; c < 4; ++c) acc[i][c] = 0.0;
    for (int h = 0; h < HH; ++h) {
        const float w0 = w1[(size_t)h * SS + lane];
        const float wc1 = w1[(size_t)h * SS + 64 + lane];
        const float wc2 = w1[(size_t)h * SS + 128 + lane];
        const float wc3 = w1[(size_t)h * SS + 192 + lane];
#pragma unroll
        for (int ii = 0; ii < 4; ++ii) {
            const double x0 = (double)xs[wv_ * 4 + ii][h];
            acc[ii][0] += x0 * (double)w0;  acc[ii][1] += x0 * (double)wc1;
            acc[ii][2] += x0 * (double)wc2; acc[ii][3] += x0 * (double)wc3;
        }
    }
    const double b2v = (double)b2[0];
#pragma unroll
    for (int ii = 0; ii < 4; ++ii) {
        double p = 0.0;
#pragma unroll
        for (int c = 0; c < 4; ++c) {
            const int scol = c * 64 + lane;
            double hv = acc[ii][c] + (double)b1[scol];
            hv = hv > 0.0 ? hv : 0.0;
            p += hv * (double)w2[scol];
        }
#pragma unroll
        for (int off = 32; off; off >>= 1) p += __shfl_xor(p, off, 64);
        if (lane == 0) {
            const size_t tok = tok0 + (size_t)wv_ * 4 + ii;
            float scf = (float)(p + b2v);
            if (mask[tok] == 0) scf = MASKED_SCORE;
            scores_out[tok] = scf;
        }
    }
}

// ---------------------------------------------------------------------------
// Gather: 512 blocks x 16 rows each, float4 per thread.
// ---------------------------------------------------------------------------
__global__ __launch_bounds__(256) void tbf_gather(
    const float* __restrict__ tokens,
    const float* __restrict__ idx_out,
    const int* __restrict__ mask,
    float* __restrict__ gathered)
{
    const int base = blockIdx.x * 16;
    const int tid  = threadIdx.x;
#pragma unroll
    for (int it = 0; it < 16; ++it) {
        const int bj = base + it;
        const int b  = bj >> 10;
        const int n  = (int)idx_out[bj];
        const int m  = mask[(size_t)b * NN + n];
        const float4* src =
            reinterpret_cast<const float4*>(tokens + ((size_t)b * NN + n) * HH);
        float4* dst = reinterpret_cast<float4*>(gathered + (size_t)bj * HH);
        float4 v = src[tid];
        if (!m) v = make_float4(0.f, 0.f, 0.f, 0.f);
        dst[tid] = v;
    }
}

// ---------------------------------------------------------------------------
extern "C" void kernel_launch(void* const* d_in, const int* in_sizes, int n_in,
                              void* d_out, int out_size, void* d_ws, size_t ws_size,
                              hipStream_t stream)
{
    const float* tokens = (const float*)d_in[0];
    const float* gamma  = (const float*)d_in[1];
    const float* beta   = (const float*)d_in[2];
    const float* w1     = (const float*)d_in[3];
    const float* b1     = (const float*)d_in[4];
    const float* w2     = (const float*)d_in[5];
    const float* b2     = (const float*)d_in[6];
    const int*   mask   = (const int*)d_in[7];

    float* out      = (float*)d_out;
    float* gathered = out;                                   // B*K*H
    float* idx_out  = out + (size_t)BB * KK * HH;            // B*K
    float* scores   = idx_out + (size_t)BB * KK;             // B*N
    float* selmask  = scores + (size_t)BB * NN;              // B*K

    const size_t wB_bytes   = (size_t)SS * HH * 2 * sizeof(_Float16);   // 1MB
    const size_t uvb_bytes  = 2 * SS * sizeof(float);
    const size_t cand_bytes = (size_t)BB * 4096 * sizeof(unsigned long long);
    const size_t idx_bytes  = (size_t)BB * NN * sizeof(int);            // 256KB
    const size_t cnt_bytes  = BB * sizeof(int);
    const size_t need = wB_bytes + uvb_bytes + cand_bytes + idx_bytes + cnt_bytes;

    if (ws_size >= need) {
        _Float16* wB = (_Float16*)d_ws;
        float* u   = (float*)((char*)d_ws + wB_bytes);
        float* vbp = u + SS;
        unsigned long long* cand =
            (unsigned long long*)((char*)d_ws + wB_bytes + uvb_bytes);
        int* idxlist = (int*)((char*)d_ws + wB_bytes + uvb_bytes + cand_bytes);
        int* cntp    = (int*)((char*)d_ws + wB_bytes + uvb_bytes + cand_bytes + idx_bytes);

        hipLaunchKernelGGL(tbf_compact, dim3(BB), dim3(1024), 0, stream,
                           mask, idxlist, cntp);
        hipLaunchKernelGGL(tbf_prep, dim3(SS), dim3(256), 0, stream,
                           gamma, beta, w1, b1, wB, u, vbp);
        hipLaunchKernelGGL(tbf_scorer, dim3(BB * NN / 64), dim3(512), 0, stream,
                           tokens, wB, u, vbp, w2, b2, mask, idxlist, cntp, scores);
        hipLaunchKernelGGL(tbf_sortslice, dim3(BB * 4), dim3(1024), 0, stream,
                           scores, cand);
        hipLaunchKernelGGL(tbf_topk4k, dim3(BB), dim3(1024), 0, stream,
                           cand, mask, idx_out, selmask);
    } else {
        hipLaunchKernelGGL(tbf_scorer_fp64, dim3(BB * NN / 16), dim3(256), 0, stream,
                           tokens, gamma, beta, w1, b1, w2, b2, mask, scores);
        hipLaunchKernelGGL(tbf_topk_mono, dim3(BB), dim3(1024), 0, stream,
                           scores, mask, idx_out, selmask);
    }
    hipLaunchKernelGGL(tbf_gather, dim3(BB * KK / 16), dim3(256), 0, stream,
                       tokens, idx_out, mask, gathered);
}